// Round 2
// baseline (1031.216 us; speedup 1.0000x reference)
//
#include <hip/hip_runtime.h>
#include <hip/hip_bf16.h>
#include <math.h>

#define B_   2
#define L_   2048
#define D_   2048
#define H_   16
#define DH_  128
#define DFF_ 8192
#define NTOK (B_*L_)

typedef __attribute__((ext_vector_type(8))) short bf16x8;
typedef __attribute__((ext_vector_type(4))) float floatx4;
typedef unsigned short u16;

__device__ __forceinline__ u16 f2bf(float f) {
    union { float f; unsigned u; } c; c.f = f;
    unsigned r = (c.u + 0x7fffu + ((c.u >> 16) & 1u)) >> 16;
    return (u16)r;
}

__device__ __forceinline__ void async_cp16(const u16* g, u16* l) {
    __builtin_amdgcn_global_load_lds(
        (const __attribute__((address_space(1))) unsigned int*)g,
        (__attribute__((address_space(3))) unsigned int*)l,
        16, 0, 0);
}

// ---------------- fp32 -> bf16 convert ----------------
__global__ __launch_bounds__(256) void cvt_bf16(const float* __restrict__ in,
                                                u16* __restrict__ out, int n4) {
    int i = blockIdx.x * 256 + threadIdx.x;
    if (i >= n4) return;
    float4 v = ((const float4*)in)[i];
    ushort4 o = { f2bf(v.x), f2bf(v.y), f2bf(v.z), f2bf(v.w) };
    ((ushort4*)out)[i] = o;
}

// ---------------- RMSNorm: fp32 in -> bf16 out ----------------
__global__ __launch_bounds__(256) void rmsnorm_kernel(const float* __restrict__ x,
                                                      const float* __restrict__ w,
                                                      u16* __restrict__ out) {
    const int row = blockIdx.x, tid = threadIdx.x;
    const float* xr = x + (size_t)row * D_;
    float4 a = ((const float4*)xr)[tid];
    float4 b = ((const float4*)xr)[tid + 256];
    float ss = a.x*a.x + a.y*a.y + a.z*a.z + a.w*a.w
             + b.x*b.x + b.y*b.y + b.z*b.z + b.w*b.w;
#pragma unroll
    for (int d = 1; d < 64; d <<= 1) ss += __shfl_xor(ss, d, 64);
    __shared__ float sred[4];
    if ((tid & 63) == 0) sred[tid >> 6] = ss;
    __syncthreads();
    float tot = sred[0] + sred[1] + sred[2] + sred[3];
    float inv = 1.0f / sqrtf(tot * (1.0f / D_) + 1e-8f);
    float4 w0 = ((const float4*)w)[tid];
    float4 w1 = ((const float4*)w)[tid + 256];
    ushort4 o0 = { f2bf(a.x*inv*w0.x), f2bf(a.y*inv*w0.y), f2bf(a.z*inv*w0.z), f2bf(a.w*inv*w0.w) };
    ushort4 o1 = { f2bf(b.x*inv*w1.x), f2bf(b.y*inv*w1.y), f2bf(b.z*inv*w1.z), f2bf(b.w*inv*w1.w) };
    ushort4* orow = (ushort4*)(out + (size_t)row * D_);
    orow[tid] = o0;
    orow[tid + 256] = o1;
}

// ---------------- 256x256 8-phase GEMM: C[M,N] = A[M,K] * W[N,K]^T ----------------
// Plain-HIP port of the verified 256^2 8-phase template (learn_hip m201):
//   BK=64, 8 waves (2M x 4N), per-wave 128x64 output, LDS 128 KiB double-buffer.
//   T2: st_16x32 XOR swizzle, applied as pre-swizzled GLOBAL source (linear LDS
//       dest for global_load_lds) + swizzled ds_read address (involution).
//   T3/T4: 4 phases per K-tile; each phase {ds_read frags | stage 2x
//       global_load_lds | barrier | lgkmcnt(0)+sched_barrier | setprio(1)
//       16xMFMA setprio(0) | barrier}. vmcnt(6) ONCE per K-tile (3 stage-units
//       in flight), never 0 in steady state. Staging targets only
//       barrier-proven-dead LDS regions: B(buf) dead after P0 (bfr reads at
//       tile top drained by P0's lgkmcnt), A granules {0,2} dead after P1,
//       {1,3} dead after P3.
// Requires: M%256==0, N%256==0, K%128==0 (NT even).
// MODE 0: fused Q/K projection (n<D_ -> outp scaled Q, else outp2 K), [B,H,L,DH]
// MODE 1: fp32 out = acc + residual
// MODE 2: bf16 out with exact-erf GELU
// MODE 3: bf16 out plain
template<int MODE>
__global__ __launch_bounds__(512, 2) void gemm256(const u16* __restrict__ A,
                                                  const u16* __restrict__ Bw,
                                                  void* __restrict__ outp,
                                                  void* __restrict__ outp2,
                                                  const float* __restrict__ residual,
                                                  int M, int N, int K, float scale) {
    __shared__ __attribute__((aligned(16))) u16 lds_a[2][256 * 64];
    __shared__ __attribute__((aligned(16))) u16 lds_b[2][256 * 64];
    const int tid = threadIdx.x;
    const int wave = tid >> 6, lane = tid & 63;
    const int qd = lane >> 4, c16 = lane & 15;
    const int wm = wave >> 2, wn = wave & 3;
    const long tile_m = (long)blockIdx.y * 256, tile_n = (long)blockIdx.x * 256;
    const int NT = K >> 6;   // number of BK=64 K-tiles (even)

    // Staging: LDS[o] = G[o ^ (bit9(o)<<5)]  => per-thread pre-swizzled source col.
    // One granule = 64 rows x 64 cols = 8 KiB = 512 threads x 16 B (linear dest;
    // per-wave dest byte = granule_base + lane*16, satisfying the
    // global_load_lds lane-contiguity rule).
    const int srow = tid >> 3;                                   // row within granule
    const int scol = ((tid & 7) * 8) ^ (((tid >> 5) & 1) << 4);  // swizzled col (elems)
    const u16* Asrc = A + (tile_m + srow) * (long)K + scol;
    const u16* Bsrc = Bw + (tile_n + srow) * (long)K + scol;
    const int stoff = tid * 8;   // u16 offset of this thread's 16B slot in a granule

#define STAGE_A2(bi, g0, g1, ko) do { \
        async_cp16(Asrc + (long)(g0) * 64 * K + (ko), &lds_a[bi][(g0) * 4096 + stoff]); \
        async_cp16(Asrc + (long)(g1) * 64 * K + (ko), &lds_a[bi][(g1) * 4096 + stoff]); \
    } while (0)
#define STAGE_B2(bi, g0, g1, ko) do { \
        async_cp16(Bsrc + (long)(g0) * 64 * K + (ko), &lds_b[bi][(g0) * 4096 + stoff]); \
        async_cp16(Bsrc + (long)(g1) * 64 * K + (ko), &lds_b[bi][(g1) * 4096 + stoff]); \
    } while (0)

    // Fragment reads: row = (wm*128|wn*64) + frag*16 + c16; byte = row*128 +
    // ks*64 + qd*16, XORed by bit9(row*128) = (c16&4) -> per-thread constant.
    const int swz = (c16 & 4) << 3;
    const int abase = (((wm * 128 + c16) * 128 + qd * 16) ^ swz);
    const int bbase = (((wn * 64 + c16) * 128 + qd * 16) ^ swz);
#define LDAF(bi, i, ks) (*(const bf16x8*)((const char*)&lds_a[bi][0] + abase + (i) * 2048 + (ks) * 64))
#define LDBF(bi, j, ks) (*(const bf16x8*)((const char*)&lds_b[bi][0] + bbase + (j) * 2048 + (ks) * 64))
#define MFMA_(a, b, c) __builtin_amdgcn_mfma_f32_16x16x32_bf16(a, b, c, 0, 0, 0)

    floatx4 acc[8][4] = {};

    // Prologue: K-tile 0 fully (8 loads) + K-tile 1 minus A-ld1 (6 loads).
    STAGE_B2(0, 0, 1, 0); STAGE_B2(0, 2, 3, 0);
    STAGE_A2(0, 0, 2, 0); STAGE_A2(0, 1, 3, 0);
    STAGE_B2(1, 0, 1, 64); STAGE_B2(1, 2, 3, 64);
    STAGE_A2(1, 0, 2, 64);
    asm volatile("s_waitcnt vmcnt(6)" ::: "memory");   // K-tile 0 landed
    __builtin_amdgcn_s_barrier();
    asm volatile("" ::: "memory");

    bf16x8 bfr[4][2];

#define GP(bi, ip, STAGE, TAIL) do { \
        bf16x8 a0k0 = LDAF(bi, 2 * (ip), 0); \
        bf16x8 a0k1 = LDAF(bi, 2 * (ip), 1); \
        bf16x8 a1k0 = LDAF(bi, 2 * (ip) + 1, 0); \
        bf16x8 a1k1 = LDAF(bi, 2 * (ip) + 1, 1); \
        STAGE \
        __builtin_amdgcn_s_barrier(); \
        asm volatile("s_waitcnt lgkmcnt(0)" ::: "memory"); \
        __builtin_amdgcn_sched_barrier(0); \
        __builtin_amdgcn_s_setprio(1); \
        _Pragma("unroll") \
        for (int j = 0; j < 4; j++) { \
            acc[2 * (ip)][j]     = MFMA_(a0k0, bfr[j][0], acc[2 * (ip)][j]); \
            acc[2 * (ip)][j]     = MFMA_(a0k1, bfr[j][1], acc[2 * (ip)][j]); \
            acc[2 * (ip) + 1][j] = MFMA_(a1k0, bfr[j][0], acc[2 * (ip) + 1][j]); \
            acc[2 * (ip) + 1][j] = MFMA_(a1k1, bfr[j][1], acc[2 * (ip) + 1][j]); \
        } \
        __builtin_amdgcn_s_setprio(0); \
        __builtin_amdgcn_sched_barrier(0); \
        TAIL \
        __builtin_amdgcn_s_barrier(); \
        asm volatile("" ::: "memory"); \
    } while (0)

#define VMTAIL { if (s2) asm volatile("s_waitcnt vmcnt(6)" ::: "memory"); \
                 else    asm volatile("s_waitcnt vmcnt(0)" ::: "memory"); }

    for (int t = 0; t < NT; t += 2) {
        const int s2 = (t + 2) < NT;
        const long ko1 = (long)(t + 1) * 64;
        const long ko2 = (long)(t + 2) * 64;
        const long ko3 = (long)(t + 3) * 64;
        // ---- K-tile t (buf 0). Stages: A-ld1(t+1)->buf1; B,A-ld0(t+2)->buf0.
#pragma unroll
        for (int j = 0; j < 4; j++) { bfr[j][0] = LDBF(0, j, 0); bfr[j][1] = LDBF(0, j, 1); }
        GP(0, 0, STAGE_A2(1, 1, 3, ko1);, );
        GP(0, 1, if (s2) STAGE_B2(0, 0, 1, ko2);, );
        GP(0, 2, if (s2) STAGE_B2(0, 2, 3, ko2);, );
        GP(0, 3, if (s2) STAGE_A2(0, 0, 2, ko2);, VMTAIL);
        // ---- K-tile t+1 (buf 1). Stages: A-ld1(t+2)->buf0; B,A-ld0(t+3)->buf1.
#pragma unroll
        for (int j = 0; j < 4; j++) { bfr[j][0] = LDBF(1, j, 0); bfr[j][1] = LDBF(1, j, 1); }
        GP(1, 0, if (s2) STAGE_A2(0, 1, 3, ko2);, );
        GP(1, 1, if (s2) STAGE_B2(1, 0, 1, ko3);, );
        GP(1, 2, if (s2) STAGE_B2(1, 2, 3, ko3);, );
        GP(1, 3, if (s2) STAGE_A2(1, 0, 2, ko3);, VMTAIL);
    }

#pragma unroll
    for (int i = 0; i < 8; i++) {
#pragma unroll
        for (int j = 0; j < 4; j++) {
#pragma unroll
            for (int r = 0; r < 4; r++) {
                long m = tile_m + wm * 128 + i * 16 + qd * 4 + r;
                long n = tile_n + wn * 64 + j * 16 + c16;
                float v = acc[i][j][r];
                if (MODE == 0) {
                    long b = m >> 11, l = m & 2047;   // L_ = 2048
                    int isq = n < D_;
                    long f = n & 2047, h = f >> 7, dh = f & 127;
                    u16* dst = isq ? (u16*)outp : (u16*)outp2;
                    dst[((b * H_ + h) * (long)L_ + l) * DH_ + dh] =
                        f2bf(v * (isq ? scale : 1.0f));
                } else if (MODE == 1) {
                    long idx = m * (long)N + n;
                    ((float*)outp)[idx] = v + residual[idx];
                } else if (MODE == 2) {
                    float g = 0.5f * v * (1.0f + erff(v * 0.70710678118654752f));
                    ((u16*)outp)[m * (long)N + n] = f2bf(g);
                } else {
                    ((u16*)outp)[m * (long)N + n] = f2bf(v);
                }
            }
        }
    }
#undef GP
#undef VMTAIL
#undef STAGE_A2
#undef STAGE_B2
#undef LDAF
#undef LDBF
#undef MFMA_
}

// ---------------- Flash-style causal attention ----------------
// grid: (16 q-tile pairs, B*H heads). Block p handles q-tiles {p, 31-p}
// (uniform 33 kv-tile iterations per block). 4 waves, 16 Q rows per wave.
// V comes PRE-TRANSPOSED: VT[vfeat][token], vfeat = h*DH+dh, token = b*L+l.
#define KSTRIDE 136   // 64x128 K tile, padded
#define VSTRIDE 72    // 128x64 V^T tile, padded
#define PSTRIDE 72    // 16x64 per-wave P tile, padded
__global__ __launch_bounds__(256) void attn_kernel(const u16* __restrict__ Q,
                                                   const u16* __restrict__ K,
                                                   const u16* __restrict__ VT,
                                                   u16* __restrict__ O) {
    __shared__ __attribute__((aligned(16))) u16 kt_lds[64 * KSTRIDE];
    __shared__ __attribute__((aligned(16))) u16 vt_lds[128 * VSTRIDE];
    __shared__ __attribute__((aligned(16))) u16 p_lds[4][16 * PSTRIDE];
    const int tid = threadIdx.x;
    const int wave = tid >> 6, lane = tid & 63;
    const int qd = lane >> 4, c16 = lane & 15;
    const int pair = blockIdx.x, bh = blockIdx.y;
    const int b = bh >> 4, h = bh & 15;
    const u16* qh = Q + (size_t)bh * L_ * DH_;
    const u16* kh = K + (size_t)bh * L_ * DH_;
    const u16* vth = VT + (size_t)h * DH_ * NTOK + (size_t)b * L_;

    for (int qsel = 0; qsel < 2; ++qsel) {
        const int qt = qsel ? (31 - pair) : pair;
        const int q0 = qt * 64;

        bf16x8 qf[4];
#pragma unroll
        for (int s = 0; s < 4; s++)
            qf[s] = *(const bf16x8*)(qh + (size_t)(q0 + wave * 16 + c16) * DH_ + s * 32 + qd * 8);

        floatx4 o_acc[8] = {};
        float m_i[4], l_i[4];
#pragma unroll
        for (int r = 0; r < 4; r++) { m_i[r] = -1e30f; l_i[r] = 0.f; }

        for (int kt = 0; kt <= qt; kt++) {
            const int kv0 = kt * 64;
#pragma unroll
            for (int s = 0; s < 4; s++) {
                int c = tid + s * 256;
                int kr = c >> 4, koff = (c & 15) * 8;
                *(int4*)&kt_lds[kr * KSTRIDE + koff] =
                    *(const int4*)(kh + (size_t)(kv0 + kr) * DH_ + koff);
                int dh = c >> 3, kv8 = (c & 7) * 8;
                *(int4*)&vt_lds[dh * VSTRIDE + kv8] =
                    *(const int4*)(vth + (size_t)dh * NTOK + kv0 + kv8);
            }
            __syncthreads();

            floatx4 s_acc[4] = {};
#pragma unroll
            for (int j = 0; j < 4; j++)
#pragma unroll
                for (int s = 0; s < 4; s++) {
                    bf16x8 kf = *(const bf16x8*)&kt_lds[(j * 16 + c16) * KSTRIDE + s * 32 + qd * 8];
                    s_acc[j] = __builtin_amdgcn_mfma_f32_16x16x32_bf16(qf[s], kf, s_acc[j], 0, 0, 0);
                }

            if (kt == qt) {
#pragma unroll
                for (int j = 0; j < 4; j++)
#pragma unroll
                    for (int r = 0; r < 4; r++) {
                        int col = j * 16 + c16;
                        int row = wave * 16 + qd * 4 + r;
                        if (col > row) s_acc[j][r] = -1e30f;
                    }
            }

            float rsum[4], alpha[4];
#pragma unroll
            for (int r = 0; r < 4; r++) {
                float mx = fmaxf(fmaxf(s_acc[0][r], s_acc[1][r]), fmaxf(s_acc[2][r], s_acc[3][r]));
#pragma unroll
                for (int d = 1; d < 16; d <<= 1) mx = fmaxf(mx, __shfl_xor(mx, d, 64));
                float mnew = fmaxf(m_i[r], mx);
                alpha[r] = __expf(m_i[r] - mnew);
                m_i[r] = mnew;
                rsum[r] = 0.f;
            }
#pragma unroll
            for (int j = 0; j < 4; j++)
#pragma unroll
                for (int r = 0; r < 4; r++) {
                    float p = __expf(s_acc[j][r] - m_i[r]);
                    s_acc[j][r] = p;
                    rsum[r] += p;
                }
#pragma unroll
            for (int r = 0; r < 4; r++) {
#pragma unroll
                for (int d = 1; d < 16; d <<= 1) rsum[r] += __shfl_xor(rsum[r], d, 64);
                l_i[r] = l_i[r] * alpha[r] + rsum[r];
            }
#pragma unroll
            for (int j8 = 0; j8 < 8; j8++)
#pragma unroll
                for (int r = 0; r < 4; r++) o_acc[j8][r] *= alpha[r];

#pragma unroll
            for (int j = 0; j < 4; j++)
#pragma unroll
                for (int r = 0; r < 4; r++)
                    p_lds[wave][(qd * 4 + r) * PSTRIDE + j * 16 + c16] = f2bf(s_acc[j][r]);

#pragma unroll
            for (int s = 0; s < 2; s++) {
                bf16x8 pf = *(const bf16x8*)&p_lds[wave][c16 * PSTRIDE + s * 32 + qd * 8];
#pragma unroll
                for (int j8 = 0; j8 < 8; j8++) {
                    bf16x8 vf = *(const bf16x8*)&vt_lds[(j8 * 16 + c16) * VSTRIDE + s * 32 + qd * 8];
                    o_acc[j8] = __builtin_amdgcn_mfma_f32_16x16x32_bf16(pf, vf, o_acc[j8], 0, 0, 0);
                }
            }
            __syncthreads();
        }

        float inv_l[4];
#pragma unroll
        for (int r = 0; r < 4; r++) inv_l[r] = 1.0f / l_i[r];
#pragma unroll
        for (int j8 = 0; j8 < 8; j8++)
#pragma unroll
            for (int r = 0; r < 4; r++) {
                int l = q0 + wave * 16 + qd * 4 + r;
                int d = h * DH_ + j8 * 16 + c16;
                O[(size_t)(b * L_ + l) * D_ + d] = f2bf(o_acc[j8][r] * inv_l[r]);
            }
    }
}

// ---------------- launch ----------------
extern "C" void kernel_launch(void* const* d_in, const int* in_sizes, int n_in,
                              void* d_out, int out_size, void* d_ws, size_t ws_size,
                              hipStream_t stream) {
    const float* x     = (const float*)d_in[0];
    const float* ln1_w = (const float*)d_in[2];
    const float* wq    = (const float*)d_in[3];
    const float* wk    = (const float*)d_in[4];
    const float* wv    = (const float*)d_in[5];
    const float* wo    = (const float*)d_in[6];
    const float* ln2_w = (const float*)d_in[7];
    const float* w_up  = (const float*)d_in[8];
    const float* w_dn  = (const float*)d_in[9];

    char* ws = (char*)d_ws;
    const size_t MB = 1024 * 1024;
    float* x2   = (float*)(ws + 0);          // 32 MB, live to end
    u16* hbuf   = (u16*)(ws + 32 * MB);      // 16 MB, h then h2
    u16* qbuf   = (u16*)(ws + 48 * MB);      // 16 MB
    u16* kbuf   = (u16*)(ws + 64 * MB);      // 16 MB
    u16* vtbuf  = (u16*)(ws + 80 * MB);      // 16 MB  V^T [D][NTOK]
    u16* attnb  = (u16*)(ws + 96 * MB);      // 16 MB
    u16* upbuf  = (u16*)(ws + 48 * MB);      // 64 MB, aliases q/k/vt/attn (dead)
    u16* wbufA  = (u16*)(ws + 112 * MB);     // 32 MB: wq+wk fused / wo / w_up / w_down
    u16* wbufC  = (u16*)(ws + 128 * MB);     // 8 MB: wv

    dim3 blk(256), blk512(512);
    const int nW = D_ * D_;      // 4M
    const int nU = DFF_ * D_;    // 16M
    // fused QK weight: [wq ; wk] = [2D, D]
    cvt_bf16<<<(nW / 4 + 255) / 256, blk, 0, stream>>>(wq, wbufA, nW / 4);
    cvt_bf16<<<(nW / 4 + 255) / 256, blk, 0, stream>>>(wk, wbufA + (size_t)nW, nW / 4);
    cvt_bf16<<<(nW / 4 + 255) / 256, blk, 0, stream>>>(wv, wbufC, nW / 4);
    rmsnorm_kernel<<<NTOK, blk, 0, stream>>>(x, ln1_w, hbuf);

    // fused Q+K projection: N = 2*D  (grid 16x16 = 256 blocks, 1/CU)
    gemm256<0><<<dim3(2 * D_ / 256, NTOK / 256), blk512, 0, stream>>>(
        hbuf, wbufA, qbuf, kbuf, nullptr, NTOK, 2 * D_, D_, 0.08838834764831845f);
    // V^T = Wv @ h^T : swapped operands, output [vfeat][token] row-major
    gemm256<3><<<dim3(NTOK / 256, D_ / 256), blk512, 0, stream>>>(
        wbufC, hbuf, vtbuf, nullptr, nullptr, D_, NTOK, D_, 1.0f);

    dim3 ga(16, B_ * H_);                    // paired q-tiles x heads
    attn_kernel<<<ga, blk, 0, stream>>>(qbuf, kbuf, vtbuf, attnb);

    cvt_bf16<<<(nW / 4 + 255) / 256, blk, 0, stream>>>(wo, wbufA, nW / 4);
    gemm256<1><<<dim3(D_ / 256, NTOK / 256), blk512, 0, stream>>>(
        attnb, wbufA, x2, nullptr, x, NTOK, D_, D_, 1.0f);

    rmsnorm_kernel<<<NTOK, blk, 0, stream>>>(x2, ln2_w, hbuf);

    cvt_bf16<<<(nU / 4 + 255) / 256, blk, 0, stream>>>(w_up, wbufA, nU / 4);
    gemm256<2><<<dim3(DFF_ / 256, NTOK / 256), blk512, 0, stream>>>(
        hbuf, wbufA, upbuf, nullptr, nullptr, NTOK, DFF_, D_, 1.0f);

    cvt_bf16<<<(nU / 4 + 255) / 256, blk, 0, stream>>>(w_dn, wbufA, nU / 4);
    gemm256<1><<<dim3(D_ / 256, NTOK / 256), blk512, 0, stream>>>(
        upbuf, wbufA, (float*)d_out, nullptr, x2, NTOK, D_, DFF_, 1.0f);
}

// Round 4
// 792.647 us; speedup vs baseline: 1.3010x; 1.3010x over previous
//
#include <hip/hip_runtime.h>
#include <hip/hip_bf16.h>
#include <math.h>

#define B_   2
#define L_   2048
#define D_   2048
#define H_   16
#define DH_  128
#define DFF_ 8192
#define NTOK (B_*L_)

typedef __attribute__((ext_vector_type(8))) short bf16x8;
typedef __attribute__((ext_vector_type(4))) float floatx4;
typedef unsigned short u16;

__device__ __forceinline__ u16 f2bf(float f) {
    union { float f; unsigned u; } c; c.f = f;
    unsigned r = (c.u + 0x7fffu + ((c.u >> 16) & 1u)) >> 16;
    return (u16)r;
}

__device__ __forceinline__ void async_cp16(const u16* g, u16* l) {
    __builtin_amdgcn_global_load_lds(
        (const __attribute__((address_space(1))) unsigned int*)g,
        (__attribute__((address_space(3))) unsigned int*)l,
        16, 0, 0);
}

// ---------------- fp32 -> bf16 convert ----------------
__global__ __launch_bounds__(256) void cvt_bf16(const float* __restrict__ in,
                                                u16* __restrict__ out, int n4) {
    int i = blockIdx.x * 256 + threadIdx.x;
    if (i >= n4) return;
    float4 v = ((const float4*)in)[i];
    ushort4 o = { f2bf(v.x), f2bf(v.y), f2bf(v.z), f2bf(v.w) };
    ((ushort4*)out)[i] = o;
}

// ---------------- RMSNorm: fp32 in -> bf16 out ----------------
__global__ __launch_bounds__(256) void rmsnorm_kernel(const float* __restrict__ x,
                                                      const float* __restrict__ w,
                                                      u16* __restrict__ out) {
    const int row = blockIdx.x, tid = threadIdx.x;
    const float* xr = x + (size_t)row * D_;
    float4 a = ((const float4*)xr)[tid];
    float4 b = ((const float4*)xr)[tid + 256];
    float ss = a.x*a.x + a.y*a.y + a.z*a.z + a.w*a.w
             + b.x*b.x + b.y*b.y + b.z*b.z + b.w*b.w;
#pragma unroll
    for (int d = 1; d < 64; d <<= 1) ss += __shfl_xor(ss, d, 64);
    __shared__ float sred[4];
    if ((tid & 63) == 0) sred[tid >> 6] = ss;
    __syncthreads();
    float tot = sred[0] + sred[1] + sred[2] + sred[3];
    float inv = 1.0f / sqrtf(tot * (1.0f / D_) + 1e-8f);
    float4 w0 = ((const float4*)w)[tid];
    float4 w1 = ((const float4*)w)[tid + 256];
    ushort4 o0 = { f2bf(a.x*inv*w0.x), f2bf(a.y*inv*w0.y), f2bf(a.z*inv*w0.z), f2bf(a.w*inv*w0.w) };
    ushort4 o1 = { f2bf(b.x*inv*w1.x), f2bf(b.y*inv*w1.y), f2bf(b.z*inv*w1.z), f2bf(b.w*inv*w1.w) };
    ushort4* orow = (ushort4*)(out + (size_t)row * D_);
    orow[tid] = o0;
    orow[tid + 256] = o1;
}

// Swizzle scheme (both GEMM kernels):
//   LDS[row][slot] = G[row][slot ^ (row&7)]   (slot = 16B chunk, 8 per 64-elem row)
//   Write: global_load_lds linear dest (tid*16B); source col pre-permuted.
//   Read:  byte-in-row = (qd*16 + ks*64) ^ ((c16&7)<<4).
//   A qd-group's 16 lanes land in 8 distinct slots x2 => 2-way = conflict-free.

// ---------------- 256x256 4-phase/K-tile GEMM: C[M,N] = A[M,K] * W[N,K]^T ----
// 8 waves (2M x 4N), per-wave 128x64 out, BK=64, 128 KiB LDS dbuf,
// counted vmcnt(6), setprio around MFMA. Requires M%256==0, N%256==0, K%128==0.
// MODE 0: fused Q/K projection (n<D_ -> outp scaled Q, else outp2 K), [B,H,L,DH]
// MODE 1: fp32 out = acc + residual
// MODE 2: bf16 out with exact-erf GELU
// MODE 3: bf16 out plain
template<int MODE>
__global__ __launch_bounds__(512, 2) void gemm256(const u16* __restrict__ A,
                                                  const u16* __restrict__ Bw,
                                                  void* __restrict__ outp,
                                                  void* __restrict__ outp2,
                                                  const float* __restrict__ residual,
                                                  int M, int N, int K, float scale) {
    __shared__ __attribute__((aligned(16))) u16 lds_a[2][256 * 64];
    __shared__ __attribute__((aligned(16))) u16 lds_b[2][256 * 64];
    const int tid = threadIdx.x;
    const int wave = tid >> 6, lane = tid & 63;
    const int qd = lane >> 4, c16 = lane & 15;
    const int wm = wave >> 2, wn = wave & 3;
    // XCD-bijective block swizzle (grid %8 == 0 for all call sites)
    const int gx = gridDim.x;
    const int nwg = gx * gridDim.y;
    const int orig = blockIdx.y * gx + blockIdx.x;
    const int id2 = (orig & 7) * (nwg >> 3) + (orig >> 3);
    const long tile_m = (long)(id2 / gx) * 256, tile_n = (long)(id2 % gx) * 256;
    const int NT = K >> 6;

    const int srow = tid >> 3;                                     // row in granule
    const int scol = (((tid & 7) ^ (srow & 7))) * 8;               // swizzled col (elems)
    const u16* Asrc = A + (tile_m + srow) * (long)K + scol;
    const u16* Bsrc = Bw + (tile_n + srow) * (long)K + scol;
    const int stoff = tid * 8;   // linear 16B slot in granule

#define STAGE_A2(bi, g0, g1, ko) do { \
        async_cp16(Asrc + (long)(g0) * 64 * K + (ko), &lds_a[bi][(g0) * 4096 + stoff]); \
        async_cp16(Asrc + (long)(g1) * 64 * K + (ko), &lds_a[bi][(g1) * 4096 + stoff]); \
    } while (0)
#define STAGE_B2(bi, g0, g1, ko) do { \
        async_cp16(Bsrc + (long)(g0) * 64 * K + (ko), &lds_b[bi][(g0) * 4096 + stoff]); \
        async_cp16(Bsrc + (long)(g1) * 64 * K + (ko), &lds_b[bi][(g1) * 4096 + stoff]); \
    } while (0)

    const int csw = (qd * 16) ^ ((c16 & 7) << 4);
    const int arowb = (wm * 128 + c16) * 128;
    const int browb = (wn * 64 + c16) * 128;
#define LDAF(bi, i, ks) (*(const bf16x8*)((const char*)&lds_a[bi][0] + arowb + (i) * 2048 + (csw ^ ((ks) * 64))))
#define LDBF(bi, j, ks) (*(const bf16x8*)((const char*)&lds_b[bi][0] + browb + (j) * 2048 + (csw ^ ((ks) * 64))))
#define MFMA_(a, b, c) __builtin_amdgcn_mfma_f32_16x16x32_bf16(a, b, c, 0, 0, 0)

    floatx4 acc[8][4] = {};

    // Prologue: K-tile 0 (8 loads) + K-tile 1 minus A-ld1 (6 loads).
    STAGE_B2(0, 0, 1, 0); STAGE_B2(0, 2, 3, 0);
    STAGE_A2(0, 0, 2, 0); STAGE_A2(0, 1, 3, 0);
    STAGE_B2(1, 0, 1, 64); STAGE_B2(1, 2, 3, 64);
    STAGE_A2(1, 0, 2, 64);
    asm volatile("s_waitcnt vmcnt(6)" ::: "memory");   // K-tile 0 landed
    __builtin_amdgcn_s_barrier();
    asm volatile("" ::: "memory");

    bf16x8 bfr[4][2];

#define GP(bi, ip, STAGE, TAIL) do { \
        bf16x8 a0k0 = LDAF(bi, 2 * (ip), 0); \
        bf16x8 a0k1 = LDAF(bi, 2 * (ip), 1); \
        bf16x8 a1k0 = LDAF(bi, 2 * (ip) + 1, 0); \
        bf16x8 a1k1 = LDAF(bi, 2 * (ip) + 1, 1); \
        STAGE \
        __builtin_amdgcn_s_barrier(); \
        asm volatile("s_waitcnt lgkmcnt(0)" ::: "memory"); \
        __builtin_amdgcn_sched_barrier(0); \
        __builtin_amdgcn_s_setprio(1); \
        _Pragma("unroll") \
        for (int j = 0; j < 4; j++) { \
            acc[2 * (ip)][j]     = MFMA_(a0k0, bfr[j][0], acc[2 * (ip)][j]); \
            acc[2 * (ip)][j]     = MFMA_(a0k1, bfr[j][1], acc[2 * (ip)][j]); \
            acc[2 * (ip) + 1][j] = MFMA_(a1k0, bfr[j][0], acc[2 * (ip) + 1][j]); \
            acc[2 * (ip) + 1][j] = MFMA_(a1k1, bfr[j][1], acc[2 * (ip) + 1][j]); \
        } \
        __builtin_amdgcn_s_setprio(0); \
        __builtin_amdgcn_sched_barrier(0); \
        TAIL \
        __builtin_amdgcn_s_barrier(); \
        asm volatile("" ::: "memory"); \
    } while (0)

#define VMTAIL { if (s2) asm volatile("s_waitcnt vmcnt(6)" ::: "memory"); \
                 else    asm volatile("s_waitcnt vmcnt(0)" ::: "memory"); }

    for (int t = 0; t < NT; t += 2) {
        const int s2 = (t + 2) < NT;
        const long ko1 = (long)(t + 1) * 64;
        const long ko2 = (long)(t + 2) * 64;
        const long ko3 = (long)(t + 3) * 64;
        // ---- K-tile t (buf 0)
#pragma unroll
        for (int j = 0; j < 4; j++) { bfr[j][0] = LDBF(0, j, 0); bfr[j][1] = LDBF(0, j, 1); }
        GP(0, 0, STAGE_A2(1, 1, 3, ko1);, );
        GP(0, 1, if (s2) STAGE_B2(0, 0, 1, ko2);, );
        GP(0, 2, if (s2) STAGE_B2(0, 2, 3, ko2);, );
        GP(0, 3, if (s2) STAGE_A2(0, 0, 2, ko2);, VMTAIL);
        // ---- K-tile t+1 (buf 1)
#pragma unroll
        for (int j = 0; j < 4; j++) { bfr[j][0] = LDBF(1, j, 0); bfr[j][1] = LDBF(1, j, 1); }
        GP(1, 0, if (s2) STAGE_A2(0, 1, 3, ko2);, );
        GP(1, 1, if (s2) STAGE_B2(1, 0, 1, ko3);, );
        GP(1, 2, if (s2) STAGE_B2(1, 2, 3, ko3);, );
        GP(1, 3, if (s2) STAGE_A2(1, 0, 2, ko3);, VMTAIL);
    }

#pragma unroll
    for (int i = 0; i < 8; i++) {
#pragma unroll
        for (int j = 0; j < 4; j++) {
#pragma unroll
            for (int r = 0; r < 4; r++) {
                long m = tile_m + wm * 128 + i * 16 + qd * 4 + r;
                long n = tile_n + wn * 64 + j * 16 + c16;
                float v = acc[i][j][r];
                if (MODE == 0) {
                    long b = m >> 11, l = m & 2047;   // L_ = 2048
                    int isq = n < D_;
                    long f = n & 2047, h = f >> 7, dh = f & 127;
                    u16* dst = isq ? (u16*)outp : (u16*)outp2;
                    dst[((b * H_ + h) * (long)L_ + l) * DH_ + dh] =
                        f2bf(v * (isq ? scale : 1.0f));
                } else if (MODE == 1) {
                    long idx = m * (long)N + n;
                    ((float*)outp)[idx] = v + residual[idx];
                } else if (MODE == 2) {
                    float g = 0.5f * v * (1.0f + erff(v * 0.70710678118654752f));
                    ((u16*)outp)[m * (long)N + n] = f2bf(g);
                } else {
                    ((u16*)outp)[m * (long)N + n] = f2bf(v);
                }
            }
        }
    }
#undef GP
#undef VMTAIL
#undef STAGE_A2
#undef STAGE_B2
#undef LDAF
#undef LDBF
#undef MFMA_
}

// ---------------- 128x256 2-phase/K-tile GEMM (for grids that would be <256
// blocks at 256^2): BM=128, BN=256, 8 waves (2M x 4N), per-wave 64x64 out,
// 96 KiB LDS dbuf. Per tile: stage A(t+1)@P0 (2 loads), B(t+2)@P1 (4 loads),
// tail vmcnt(4). Requires M%128==0, N%256==0, K%128==0.
// MODE 1: fp32 out = acc + residual;  MODE 3: bf16 out plain.
template<int MODE>
__global__ __launch_bounds__(512, 2) void gemm128n(const u16* __restrict__ A,
                                                   const u16* __restrict__ Bw,
                                                   void* __restrict__ outp,
                                                   const float* __restrict__ residual,
                                                   int M, int N, int K) {
    __shared__ __attribute__((aligned(16))) u16 lds_a[2][128 * 64];
    __shared__ __attribute__((aligned(16))) u16 lds_b[2][256 * 64];
    const int tid = threadIdx.x;
    const int wave = tid >> 6, lane = tid & 63;
    const int qd = lane >> 4, c16 = lane & 15;
    const int wm = wave >> 2, wn = wave & 3;
    const int gx = gridDim.x;
    const int nwg = gx * gridDim.y;
    const int orig = blockIdx.y * gx + blockIdx.x;
    const int id2 = (orig & 7) * (nwg >> 3) + (orig >> 3);
    const long tile_m = (long)(id2 / gx) * 128, tile_n = (long)(id2 % gx) * 256;
    const int NT = K >> 6;

    const int srow = tid >> 3;
    const int scol = (((tid & 7) ^ (srow & 7))) * 8;
    const u16* Asrc = A + (tile_m + srow) * (long)K + scol;
    const u16* Bsrc = Bw + (tile_n + srow) * (long)K + scol;
    const int stoff = tid * 8;

#define STAGE_AA(bi, ko) do { \
        async_cp16(Asrc + (ko), &lds_a[bi][stoff]); \
        async_cp16(Asrc + 64 * (long)K + (ko), &lds_a[bi][4096 + stoff]); \
    } while (0)
#define STAGE_BA(bi, ko) do { \
        async_cp16(Bsrc + (ko), &lds_b[bi][stoff]); \
        async_cp16(Bsrc + 64 * (long)K + (ko), &lds_b[bi][4096 + stoff]); \
        async_cp16(Bsrc + 128 * (long)K + (ko), &lds_b[bi][8192 + stoff]); \
        async_cp16(Bsrc + 192 * (long)K + (ko), &lds_b[bi][12288 + stoff]); \
    } while (0)

    const int csw = (qd * 16) ^ ((c16 & 7) << 4);
    const int arowb = (wm * 64 + c16) * 128;
    const int browb = (wn * 64 + c16) * 128;
#define LDAF2(bi, i, ks) (*(const bf16x8*)((const char*)&lds_a[bi][0] + arowb + (i) * 2048 + (csw ^ ((ks) * 64))))
#define LDBF2(bi, j, ks) (*(const bf16x8*)((const char*)&lds_b[bi][0] + browb + (j) * 2048 + (csw ^ ((ks) * 64))))
#define MFMA_(a, b, c) __builtin_amdgcn_mfma_f32_16x16x32_bf16(a, b, c, 0, 0, 0)

    floatx4 acc[4][4] = {};

    // Prologue: tile0 (6 loads) + tile1 B (4 loads); A(1) staged inside tile 0.
    STAGE_BA(0, 0); STAGE_AA(0, 0); STAGE_BA(1, 64);
    asm volatile("s_waitcnt vmcnt(4)" ::: "memory");   // tile 0 landed
    __builtin_amdgcn_s_barrier();
    asm volatile("" ::: "memory");

    bf16x8 bfr[4][2];

#define GP2(bi, ip, STAGE, TAIL) do { \
        bf16x8 a0k0 = LDAF2(bi, 2 * (ip), 0); \
        bf16x8 a0k1 = LDAF2(bi, 2 * (ip), 1); \
        bf16x8 a1k0 = LDAF2(bi, 2 * (ip) + 1, 0); \
        bf16x8 a1k1 = LDAF2(bi, 2 * (ip) + 1, 1); \
        STAGE \
        __builtin_amdgcn_s_barrier(); \
        asm volatile("s_waitcnt lgkmcnt(0)" ::: "memory"); \
        __builtin_amdgcn_sched_barrier(0); \
        __builtin_amdgcn_s_setprio(1); \
        _Pragma("unroll") \
        for (int j = 0; j < 4; j++) { \
            acc[2 * (ip)][j]     = MFMA_(a0k0, bfr[j][0], acc[2 * (ip)][j]); \
            acc[2 * (ip)][j]     = MFMA_(a0k1, bfr[j][1], acc[2 * (ip)][j]); \
            acc[2 * (ip) + 1][j] = MFMA_(a1k0, bfr[j][0], acc[2 * (ip) + 1][j]); \
            acc[2 * (ip) + 1][j] = MFMA_(a1k1, bfr[j][1], acc[2 * (ip) + 1][j]); \
        } \
        __builtin_amdgcn_s_setprio(0); \
        __builtin_amdgcn_sched_barrier(0); \
        TAIL \
        __builtin_amdgcn_s_barrier(); \
        asm volatile("" ::: "memory"); \
    } while (0)

#define TILE2(tt, bi) do { \
        _Pragma("unroll") \
        for (int j = 0; j < 4; j++) { bfr[j][0] = LDBF2(bi, j, 0); bfr[j][1] = LDBF2(bi, j, 1); } \
        GP2(bi, 0, if ((tt) + 1 < NT) STAGE_AA(bi ^ 1, ((long)(tt) + 1) * 64);, ); \
        GP2(bi, 1, if ((tt) + 2 < NT) STAGE_BA(bi, ((long)(tt) + 2) * 64);, \
            { if ((tt) + 2 < NT) asm volatile("s_waitcnt vmcnt(4)" ::: "memory"); \
              else               asm volatile("s_waitcnt vmcnt(0)" ::: "memory"); }); \
    } while (0)

    for (int t = 0; t < NT; t += 2) {
        TILE2(t, 0);
        TILE2(t + 1, 1);
    }

#pragma unroll
    for (int i = 0; i < 4; i++) {
#pragma unroll
        for (int j = 0; j < 4; j++) {
#pragma unroll
            for (int r = 0; r < 4; r++) {
                long m = tile_m + wm * 64 + i * 16 + qd * 4 + r;
                long n = tile_n + wn * 64 + j * 16 + c16;
                float v = acc[i][j][r];
                if (MODE == 1) {
                    long idx = m * (long)N + n;
                    ((float*)outp)[idx] = v + residual[idx];
                } else {
                    ((u16*)outp)[m * (long)N + n] = f2bf(v);
                }
            }
        }
    }
#undef GP2
#undef TILE2
#undef STAGE_AA
#undef STAGE_BA
#undef LDAF2
#undef LDBF2
#undef MFMA_
}

// ---------------- Flash-style causal attention ----------------
// grid: (16 q-tile pairs, B*H heads). Block p handles q-tiles {p, 31-p}
// (uniform 33 kv-tile iterations per block). 4 waves, 16 Q rows per wave.
// V comes PRE-TRANSPOSED: VT[vfeat][token], vfeat = h*DH+dh, token = b*L+l.
#define KSTRIDE 136   // 64x128 K tile, padded
#define VSTRIDE 72    // 128x64 V^T tile, padded
#define PSTRIDE 72    // 16x64 per-wave P tile, padded
__global__ __launch_bounds__(256) void attn_kernel(const u16* __restrict__ Q,
                                                   const u16* __restrict__ K,
                                                   const u16* __restrict__ VT,
                                                   u16* __restrict__ O) {
    __shared__ __attribute__((aligned(16))) u16 kt_lds[64 * KSTRIDE];
    __shared__ __attribute__((aligned(16))) u16 vt_lds[128 * VSTRIDE];
    __shared__ __attribute__((aligned(16))) u16 p_lds[4][16 * PSTRIDE];
    const int tid = threadIdx.x;
    const int wave = tid >> 6, lane = tid & 63;
    const int qd = lane >> 4, c16 = lane & 15;
    const int pair = blockIdx.x, bh = blockIdx.y;
    const int b = bh >> 4, h = bh & 15;
    const u16* qh = Q + (size_t)bh * L_ * DH_;
    const u16* kh = K + (size_t)bh * L_ * DH_;
    const u16* vth = VT + (size_t)h * DH_ * NTOK + (size_t)b * L_;

    for (int qsel = 0; qsel < 2; ++qsel) {
        const int qt = qsel ? (31 - pair) : pair;
        const int q0 = qt * 64;

        bf16x8 qf[4];
#pragma unroll
        for (int s = 0; s < 4; s++)
            qf[s] = *(const bf16x8*)(qh + (size_t)(q0 + wave * 16 + c16) * DH_ + s * 32 + qd * 8);

        floatx4 o_acc[8] = {};
        float m_i[4], l_i[4];
#pragma unroll
        for (int r = 0; r < 4; r++) { m_i[r] = -1e30f; l_i[r] = 0.f; }

        for (int kt = 0; kt <= qt; kt++) {
            const int kv0 = kt * 64;
#pragma unroll
            for (int s = 0; s < 4; s++) {
                int c = tid + s * 256;
                int kr = c >> 4, koff = (c & 15) * 8;
                *(int4*)&kt_lds[kr * KSTRIDE + koff] =
                    *(const int4*)(kh + (size_t)(kv0 + kr) * DH_ + koff);
                int dh = c >> 3, kv8 = (c & 7) * 8;
                *(int4*)&vt_lds[dh * VSTRIDE + kv8] =
                    *(const int4*)(vth + (size_t)dh * NTOK + kv0 + kv8);
            }
            __syncthreads();

            floatx4 s_acc[4] = {};
#pragma unroll
            for (int j = 0; j < 4; j++)
#pragma unroll
                for (int s = 0; s < 4; s++) {
                    bf16x8 kf = *(const bf16x8*)&kt_lds[(j * 16 + c16) * KSTRIDE + s * 32 + qd * 8];
                    s_acc[j] = __builtin_amdgcn_mfma_f32_16x16x32_bf16(qf[s], kf, s_acc[j], 0, 0, 0);
                }

            if (kt == qt) {
#pragma unroll
                for (int j = 0; j < 4; j++)
#pragma unroll
                    for (int r = 0; r < 4; r++) {
                        int col = j * 16 + c16;
                        int row = wave * 16 + qd * 4 + r;
                        if (col > row) s_acc[j][r] = -1e30f;
                    }
            }

            float rsum[4], alpha[4];
#pragma unroll
            for (int r = 0; r < 4; r++) {
                float mx = fmaxf(fmaxf(s_acc[0][r], s_acc[1][r]), fmaxf(s_acc[2][r], s_acc[3][r]));
#pragma unroll
                for (int d = 1; d < 16; d <<= 1) mx = fmaxf(mx, __shfl_xor(mx, d, 64));
                float mnew = fmaxf(m_i[r], mx);
                alpha[r] = __expf(m_i[r] - mnew);
                m_i[r] = mnew;
                rsum[r] = 0.f;
            }
#pragma unroll
            for (int j = 0; j < 4; j++)
#pragma unroll
                for (int r = 0; r < 4; r++) {
                    float p = __expf(s_acc[j][r] - m_i[r]);
                    s_acc[j][r] = p;
                    rsum[r] += p;
                }
#pragma unroll
            for (int r = 0; r < 4; r++) {
#pragma unroll
                for (int d = 1; d < 16; d <<= 1) rsum[r] += __shfl_xor(rsum[r], d, 64);
                l_i[r] = l_i[r] * alpha[r] + rsum[r];
            }
#pragma unroll
            for (int j8 = 0; j8 < 8; j8++)
#pragma unroll
                for (int r = 0; r < 4; r++) o_acc[j8][r] *= alpha[r];

#pragma unroll
            for (int j = 0; j < 4; j++)
#pragma unroll
                for (int r = 0; r < 4; r++)
                    p_lds[wave][(qd * 4 + r) * PSTRIDE + j * 16 + c16] = f2bf(s_acc[j][r]);

#pragma unroll
            for (int s = 0; s < 2; s++) {
                bf16x8 pf = *(const bf16x8*)&p_lds[wave][c16 * PSTRIDE + s * 32 + qd * 8];
#pragma unroll
                for (int j8 = 0; j8 < 8; j8++) {
                    bf16x8 vf = *(const bf16x8*)&vt_lds[(j8 * 16 + c16) * VSTRIDE + s * 32 + qd * 8];
                    o_acc[j8] = __builtin_amdgcn_mfma_f32_16x16x32_bf16(pf, vf, o_acc[j8], 0, 0, 0);
                }
            }
            __syncthreads();
        }

        float inv_l[4];
#pragma unroll
        for (int r = 0; r < 4; r++) inv_l[r] = 1.0f / l_i[r];
#pragma unroll
        for (int j8 = 0; j8 < 8; j8++)
#pragma unroll
            for (int r = 0; r < 4; r++) {
                int l = q0 + wave * 16 + qd * 4 + r;
                int d = h * DH_ + j8 * 16 + c16;
                O[(size_t)(b * L_ + l) * D_ + d] = f2bf(o_acc[j8][r] * inv_l[r]);
            }
    }
}

// ---------------- launch ----------------
extern "C" void kernel_launch(void* const* d_in, const int* in_sizes, int n_in,
                              void* d_out, int out_size, void* d_ws, size_t ws_size,
                              hipStream_t stream) {
    const float* x     = (const float*)d_in[0];
    const float* ln1_w = (const float*)d_in[2];
    const float* wq    = (const float*)d_in[3];
    const float* wk    = (const float*)d_in[4];
    const float* wv    = (const float*)d_in[5];
    const float* wo    = (const float*)d_in[6];
    const float* ln2_w = (const float*)d_in[7];
    const float* w_up  = (const float*)d_in[8];
    const float* w_dn  = (const float*)d_in[9];

    char* ws = (char*)d_ws;
    const size_t MB = 1024 * 1024;
    float* x2   = (float*)(ws + 0);          // 32 MB, live to end
    u16* hbuf   = (u16*)(ws + 32 * MB);      // 16 MB, h then h2
    u16* qbuf   = (u16*)(ws + 48 * MB);      // 16 MB
    u16* kbuf   = (u16*)(ws + 64 * MB);      // 16 MB
    u16* vtbuf  = (u16*)(ws + 80 * MB);      // 16 MB  V^T [D][NTOK]
    u16* attnb  = (u16*)(ws + 96 * MB);      // 16 MB
    u16* upbuf  = (u16*)(ws + 48 * MB);      // 64 MB, aliases q/k/vt/attn (dead)
    u16* wbufA  = (u16*)(ws + 112 * MB);     // 32 MB: wq+wk fused / wo / w_up / w_down
    u16* wbufC  = (u16*)(ws + 128 * MB);     // 8 MB: wv

    dim3 blk(256), blk512(512);
    const int nW = D_ * D_;      // 4M
    const int nU = DFF_ * D_;    // 16M
    // fused QK weight: [wq ; wk] = [2D, D]
    cvt_bf16<<<(nW / 4 + 255) / 256, blk, 0, stream>>>(wq, wbufA, nW / 4);
    cvt_bf16<<<(nW / 4 + 255) / 256, blk, 0, stream>>>(wk, wbufA + (size_t)nW, nW / 4);
    cvt_bf16<<<(nW / 4 + 255) / 256, blk, 0, stream>>>(wv, wbufC, nW / 4);
    rmsnorm_kernel<<<NTOK, blk, 0, stream>>>(x, ln1_w, hbuf);

    // fused Q+K projection: N = 2*D  (grid 16x16 = 256 blocks)
    gemm256<0><<<dim3(2 * D_ / 256, NTOK / 256), blk512, 0, stream>>>(
        hbuf, wbufA, qbuf, kbuf, nullptr, NTOK, 2 * D_, D_, 0.08838834764831845f);
    // V^T = Wv @ h^T : swapped operands, out [vfeat][token]; grid (16,16)=256
    gemm128n<3><<<dim3(NTOK / 256, D_ / 128), blk512, 0, stream>>>(
        wbufC, hbuf, vtbuf, nullptr, D_, NTOK, D_);

    dim3 ga(16, B_ * H_);                    // paired q-tiles x heads
    attn_kernel<<<ga, blk, 0, stream>>>(qbuf, kbuf, vtbuf, attnb);

    cvt_bf16<<<(nW / 4 + 255) / 256, blk, 0, stream>>>(wo, wbufA, nW / 4);
    // WO projection + residual: grid (8,32)=256
    gemm128n<1><<<dim3(D_ / 256, NTOK / 128), blk512, 0, stream>>>(
        attnb, wbufA, x2, x, NTOK, D_, D_);

    rmsnorm_kernel<<<NTOK, blk, 0, stream>>>(x2, ln2_w, hbuf);

    cvt_bf16<<<(nU / 4 + 255) / 256, blk, 0, stream>>>(w_up, wbufA, nU / 4);
    // up-proj + GELU: grid (32,16)=512 (2 exact rounds)
    gemm256<2><<<dim3(DFF_ / 256, NTOK / 256), blk512, 0, stream>>>(
        hbuf, wbufA, upbuf, nullptr, nullptr, NTOK, DFF_, D_, 1.0f);

    cvt_bf16<<<(nU / 4 + 255) / 256, blk, 0, stream>>>(w_dn, wbufA, nU / 4);
    // down-proj + residual: grid (8,32)=256
    gemm128n<1><<<dim3(D_ / 256, NTOK / 128), blk512, 0, stream>>>(
        upbuf, wbufA, (float*)d_out, x2, NTOK, D_, DFF_);
}

// Round 5
// 765.978 us; speedup vs baseline: 1.3463x; 1.0348x over previous
//
#include <hip/hip_runtime.h>
#include <hip/hip_bf16.h>
#include <math.h>

#define B_   2
#define L_   2048
#define D_   2048
#define H_   16
#define DH_  128
#define DFF_ 8192
#define NTOK (B_*L_)

typedef __attribute__((ext_vector_type(8))) short bf16x8;
typedef __attribute__((ext_vector_type(4))) float floatx4;
typedef unsigned short u16;

__device__ __forceinline__ u16 f2bf(float f) {
    union { float f; unsigned u; } c; c.f = f;
    unsigned r = (c.u + 0x7fffu + ((c.u >> 16) & 1u)) >> 16;
    return (u16)r;
}

__device__ __forceinline__ void async_cp16(const u16* g, u16* l) {
    __builtin_amdgcn_global_load_lds(
        (const __attribute__((address_space(1))) unsigned int*)g,
        (__attribute__((address_space(3))) unsigned int*)l,
        16, 0, 0);
}

// ---------------- fp32 -> bf16 convert ----------------
__global__ __launch_bounds__(256) void cvt_bf16(const float* __restrict__ in,
                                                u16* __restrict__ out, int n4) {
    int i = blockIdx.x * 256 + threadIdx.x;
    if (i >= n4) return;
    float4 v = ((const float4*)in)[i];
    ushort4 o = { f2bf(v.x), f2bf(v.y), f2bf(v.z), f2bf(v.w) };
    ((ushort4*)out)[i] = o;
}

// ---------------- RMSNorm: fp32 in -> bf16 out ----------------
__global__ __launch_bounds__(256) void rmsnorm_kernel(const float* __restrict__ x,
                                                      const float* __restrict__ w,
                                                      u16* __restrict__ out) {
    const int row = blockIdx.x, tid = threadIdx.x;
    const float* xr = x + (size_t)row * D_;
    float4 a = ((const float4*)xr)[tid];
    float4 b = ((const float4*)xr)[tid + 256];
    float ss = a.x*a.x + a.y*a.y + a.z*a.z + a.w*a.w
             + b.x*b.x + b.y*b.y + b.z*b.z + b.w*b.w;
#pragma unroll
    for (int d = 1; d < 64; d <<= 1) ss += __shfl_xor(ss, d, 64);
    __shared__ float sred[4];
    if ((tid & 63) == 0) sred[tid >> 6] = ss;
    __syncthreads();
    float tot = sred[0] + sred[1] + sred[2] + sred[3];
    float inv = 1.0f / sqrtf(tot * (1.0f / D_) + 1e-8f);
    float4 w0 = ((const float4*)w)[tid];
    float4 w1 = ((const float4*)w)[tid + 256];
    ushort4 o0 = { f2bf(a.x*inv*w0.x), f2bf(a.y*inv*w0.y), f2bf(a.z*inv*w0.z), f2bf(a.w*inv*w0.w) };
    ushort4 o1 = { f2bf(b.x*inv*w1.x), f2bf(b.y*inv*w1.y), f2bf(b.z*inv*w1.z), f2bf(b.w*inv*w1.w) };
    ushort4* orow = (ushort4*)(out + (size_t)row * D_);
    orow[tid] = o0;
    orow[tid + 256] = o1;
}

// Swizzle (verified 0 bank conflicts in round 4):
//   LDS[row][slot] = G[row][slot ^ (row&7)]  (slot = 16B chunk, 8/row)
//   Write: linear LDS dest (tid*16B), pre-permuted global source col.
//   Read:  byte-in-row = (qd*16) ^ ((c16&7)<<4) ^ (ks*64).
//
// Schedule (this round): ONE barrier per phase; A-frags read one phase AHEAD
// into alternating reg sets; NO lgkmcnt asm / sched_barrier (backend emits
// counted lgkmcnt before first MFMA use — m97 evidence). Write-after-read
// safety: every ds_read is consumed by an MFMA >=1 barrier before any
// global_load_lds targets its region (ledger in comments below). Counted
// vmcnt preserved (never 0 in steady state).

// ---------------- 256x256 GEMM: C[M,N] = A[M,K] * W[N,K]^T ----------------
// 8 waves (2M x 4N), per-wave 128x64 out, BK=64, 128 KiB LDS dbuf.
// Stage ledger per tile t (buf c=t&1): P0: A(t+1)g1,g3->buf c^1 (g1/g3 of c^1
// last read tile t-1, drained by its MFMAs); P1: B(t+2)g0,g1->c (bfr(t) reads
// consumed in P0); P2: B(t+2)g2,g3 + A(t+2)g0->c (afA rows0-1 consumed P0/P1);
// P3: A(t+2)g2->c (afA rows4-5 consumed P2... rows128-191 consumed by P0/P1 of
// wm1). VMTAIL: 6 loads newer than tile t+1's last granule -> vmcnt(6).
// MODE 0: fused Q/K proj (n<D_ -> outp scaled Q, else outp2 K), [B,H,L,DH]
// MODE 1: fp32 out = acc + residual;  MODE 2: bf16 GELU;  MODE 3: bf16 plain
template<int MODE>
__global__ __launch_bounds__(512, 2) void gemm256(const u16* __restrict__ A,
                                                  const u16* __restrict__ Bw,
                                                  void* __restrict__ outp,
                                                  void* __restrict__ outp2,
                                                  const float* __restrict__ residual,
                                                  int M, int N, int K, float scale) {
    __shared__ __attribute__((aligned(16))) u16 lds_a[2][256 * 64];
    __shared__ __attribute__((aligned(16))) u16 lds_b[2][256 * 64];
    const int tid = threadIdx.x;
    const int wave = tid >> 6, lane = tid & 63;
    const int qd = lane >> 4, c16 = lane & 15;
    const int wm = wave >> 2, wn = wave & 3;
    const int gx = gridDim.x;
    const int nwg = gx * gridDim.y;
    const int orig = blockIdx.y * gx + blockIdx.x;
    const int id2 = (orig & 7) * (nwg >> 3) + (orig >> 3);
    const long tile_m = (long)(id2 / gx) * 256, tile_n = (long)(id2 % gx) * 256;
    const int NT = K >> 6;

    const int srow = tid >> 3;
    const int scol = (((tid & 7) ^ (srow & 7))) * 8;
    const u16* Asrc = A + (tile_m + srow) * (long)K + scol;
    const u16* Bsrc = Bw + (tile_n + srow) * (long)K + scol;
    const int stoff = tid * 8;

#define STAGE_A2(bi, g0, g1, ko) do { \
        async_cp16(Asrc + (long)(g0) * 64 * K + (ko), &lds_a[bi][(g0) * 4096 + stoff]); \
        async_cp16(Asrc + (long)(g1) * 64 * K + (ko), &lds_a[bi][(g1) * 4096 + stoff]); \
    } while (0)
#define STAGE_B2(bi, g0, g1, ko) do { \
        async_cp16(Bsrc + (long)(g0) * 64 * K + (ko), &lds_b[bi][(g0) * 4096 + stoff]); \
        async_cp16(Bsrc + (long)(g1) * 64 * K + (ko), &lds_b[bi][(g1) * 4096 + stoff]); \
    } while (0)

    const int csw = (qd * 16) ^ ((c16 & 7) << 4);
    const int arowb = (wm * 128 + c16) * 128;
    const int browb = (wn * 64 + c16) * 128;
#define LDAF(bi, i, ks) (*(const bf16x8*)((const char*)&lds_a[bi][0] + arowb + (i) * 2048 + (csw ^ ((ks) * 64))))
#define LDBF(bi, j, ks) (*(const bf16x8*)((const char*)&lds_b[bi][0] + browb + (j) * 2048 + (csw ^ ((ks) * 64))))
#define MFMA_(a, b, c) __builtin_amdgcn_mfma_f32_16x16x32_bf16(a, b, c, 0, 0, 0)

#define READ_BFR(bi) do { \
        _Pragma("unroll") \
        for (int j = 0; j < 4; j++) { bfr[j][0] = LDBF(bi, j, 0); bfr[j][1] = LDBF(bi, j, 1); } \
    } while (0)
#define READ_AF(dst, bi, r0) do { \
        dst[0] = LDAF(bi, r0, 0); dst[1] = LDAF(bi, r0, 1); \
        dst[2] = LDAF(bi, (r0) + 1, 0); dst[3] = LDAF(bi, (r0) + 1, 1); \
    } while (0)
#define MFMA_PH(af, R) do { \
        __builtin_amdgcn_s_setprio(1); \
        _Pragma("unroll") \
        for (int j = 0; j < 4; j++) { \
            acc[R][j]       = MFMA_(af[0], bfr[j][0], acc[R][j]); \
            acc[R][j]       = MFMA_(af[1], bfr[j][1], acc[R][j]); \
            acc[(R) + 1][j] = MFMA_(af[2], bfr[j][0], acc[(R) + 1][j]); \
            acc[(R) + 1][j] = MFMA_(af[3], bfr[j][1], acc[(R) + 1][j]); \
        } \
        __builtin_amdgcn_s_setprio(0); \
    } while (0)

    floatx4 acc[8][4] = {};
    bf16x8 bfr[4][2];

    // Prologue: tile0 (8 loads, oldest) + tile1 minus A g1,g3 (6 loads).
    STAGE_B2(0, 0, 1, 0); STAGE_B2(0, 2, 3, 0);
    STAGE_A2(0, 0, 2, 0); STAGE_A2(0, 1, 3, 0);
    STAGE_B2(1, 0, 1, 64); STAGE_B2(1, 2, 3, 64);
    STAGE_A2(1, 0, 2, 64);
    asm volatile("s_waitcnt vmcnt(6)" ::: "memory");   // tile0 landed
    __builtin_amdgcn_s_barrier();

#define TILE256(bi, koN, koNN, GA1, GS) do { \
        READ_BFR(bi); \
        bf16x8 afA[4], afB[4]; \
        READ_AF(afA, bi, 0); \
        /* P0 */ \
        READ_AF(afB, bi, 2); \
        if (GA1) STAGE_A2((bi) ^ 1, 1, 3, koN); \
        MFMA_PH(afA, 0); \
        __builtin_amdgcn_s_barrier(); \
        /* P1 */ \
        READ_AF(afA, bi, 4); \
        if (GS) STAGE_B2(bi, 0, 1, koNN); \
        MFMA_PH(afB, 2); \
        __builtin_amdgcn_s_barrier(); \
        /* P2 */ \
        READ_AF(afB, bi, 6); \
        if (GS) STAGE_B2(bi, 2, 3, koNN); \
        MFMA_PH(afA, 4); \
        __builtin_amdgcn_s_barrier(); \
        /* P3 */ \
        if (GS) STAGE_A2(bi, 0, 2, koNN); \
        MFMA_PH(afB, 6); \
        if (GS) asm volatile("s_waitcnt vmcnt(6)" ::: "memory"); \
        else    asm volatile("s_waitcnt vmcnt(0)" ::: "memory"); \
        __builtin_amdgcn_s_barrier(); \
    } while (0)

    for (int t = 0; t < NT; t += 2) {
        const int s2 = (t + 2) < NT;
        const long ko1 = (long)(t + 1) * 64;
        const long ko2 = (long)(t + 2) * 64;
        const long ko3 = (long)(t + 3) * 64;
        TILE256(0, ko1, ko2, 1, s2);
        TILE256(1, ko2, ko3, s2, s2);
    }

#pragma unroll
    for (int i = 0; i < 8; i++) {
#pragma unroll
        for (int j = 0; j < 4; j++) {
#pragma unroll
            for (int r = 0; r < 4; r++) {
                long m = tile_m + wm * 128 + i * 16 + qd * 4 + r;
                long n = tile_n + wn * 64 + j * 16 + c16;
                float v = acc[i][j][r];
                if (MODE == 0) {
                    long b = m >> 11, l = m & 2047;   // L_ = 2048
                    int isq = n < D_;
                    long f = n & 2047, h = f >> 7, dh = f & 127;
                    u16* dst = isq ? (u16*)outp : (u16*)outp2;
                    dst[((b * H_ + h) * (long)L_ + l) * DH_ + dh] =
                        f2bf(v * (isq ? scale : 1.0f));
                } else if (MODE == 1) {
                    long idx = m * (long)N + n;
                    ((float*)outp)[idx] = v + residual[idx];
                } else if (MODE == 2) {
                    float g = 0.5f * v * (1.0f + erff(v * 0.70710678118654752f));
                    ((u16*)outp)[m * (long)N + n] = f2bf(g);
                } else {
                    ((u16*)outp)[m * (long)N + n] = f2bf(v);
                }
            }
        }
    }
#undef TILE256
#undef READ_BFR
#undef READ_AF
#undef MFMA_PH
#undef STAGE_A2
#undef STAGE_B2
#undef LDAF
#undef LDBF
#undef MFMA_
}

// ---------------- 128x256 GEMM: BM=128, BN=256, 8 waves (2M x 4N), ------
// per-wave 64x64 out, 96 KiB LDS dbuf, 2 phases/K-tile, 1 barrier/phase.
// Stage ledger: P0: A(t+1) both granules -> buf c^1 (its reads done tile t-1);
// P1: B(t+2) -> buf c (bfr(t) consumed P0). VMTAIL: 4 newer -> vmcnt(4).
// MODE 1: fp32 out = acc + residual;  MODE 3: bf16 out plain.
template<int MODE>
__global__ __launch_bounds__(512, 2) void gemm128n(const u16* __restrict__ A,
                                                   const u16* __restrict__ Bw,
                                                   void* __restrict__ outp,
                                                   const float* __restrict__ residual,
                                                   int M, int N, int K) {
    __shared__ __attribute__((aligned(16))) u16 lds_a[2][128 * 64];
    __shared__ __attribute__((aligned(16))) u16 lds_b[2][256 * 64];
    const int tid = threadIdx.x;
    const int wave = tid >> 6, lane = tid & 63;
    const int qd = lane >> 4, c16 = lane & 15;
    const int wm = wave >> 2, wn = wave & 3;
    const int gx = gridDim.x;
    const int nwg = gx * gridDim.y;
    const int orig = blockIdx.y * gx + blockIdx.x;
    const int id2 = (orig & 7) * (nwg >> 3) + (orig >> 3);
    const long tile_m = (long)(id2 / gx) * 128, tile_n = (long)(id2 % gx) * 256;
    const int NT = K >> 6;

    const int srow = tid >> 3;
    const int scol = (((tid & 7) ^ (srow & 7))) * 8;
    const u16* Asrc = A + (tile_m + srow) * (long)K + scol;
    const u16* Bsrc = Bw + (tile_n + srow) * (long)K + scol;
    const int stoff = tid * 8;

#define STAGE_AA(bi, ko) do { \
        async_cp16(Asrc + (ko), &lds_a[bi][stoff]); \
        async_cp16(Asrc + 64 * (long)K + (ko), &lds_a[bi][4096 + stoff]); \
    } while (0)
#define STAGE_BA(bi, ko) do { \
        async_cp16(Bsrc + (ko), &lds_b[bi][stoff]); \
        async_cp16(Bsrc + 64 * (long)K + (ko), &lds_b[bi][4096 + stoff]); \
        async_cp16(Bsrc + 128 * (long)K + (ko), &lds_b[bi][8192 + stoff]); \
        async_cp16(Bsrc + 192 * (long)K + (ko), &lds_b[bi][12288 + stoff]); \
    } while (0)

    const int csw = (qd * 16) ^ ((c16 & 7) << 4);
    const int arowb = (wm * 64 + c16) * 128;
    const int browb = (wn * 64 + c16) * 128;
#define LDAF2(bi, i, ks) (*(const bf16x8*)((const char*)&lds_a[bi][0] + arowb + (i) * 2048 + (csw ^ ((ks) * 64))))
#define LDBF2(bi, j, ks) (*(const bf16x8*)((const char*)&lds_b[bi][0] + browb + (j) * 2048 + (csw ^ ((ks) * 64))))
#define MFMA_(a, b, c) __builtin_amdgcn_mfma_f32_16x16x32_bf16(a, b, c, 0, 0, 0)

#define READ_BFR2(bi) do { \
        _Pragma("unroll") \
        for (int j = 0; j < 4; j++) { bfr[j][0] = LDBF2(bi, j, 0); bfr[j][1] = LDBF2(bi, j, 1); } \
    } while (0)
#define READ_AF2(dst, bi, r0) do { \
        dst[0] = LDAF2(bi, r0, 0); dst[1] = LDAF2(bi, r0, 1); \
        dst[2] = LDAF2(bi, (r0) + 1, 0); dst[3] = LDAF2(bi, (r0) + 1, 1); \
    } while (0)
#define MFMA_PH2(af, R) do { \
        __builtin_amdgcn_s_setprio(1); \
        _Pragma("unroll") \
        for (int j = 0; j < 4; j++) { \
            acc[R][j]       = MFMA_(af[0], bfr[j][0], acc[R][j]); \
            acc[R][j]       = MFMA_(af[1], bfr[j][1], acc[R][j]); \
            acc[(R) + 1][j] = MFMA_(af[2], bfr[j][0], acc[(R) + 1][j]); \
            acc[(R) + 1][j] = MFMA_(af[3], bfr[j][1], acc[(R) + 1][j]); \
        } \
        __builtin_amdgcn_s_setprio(0); \
    } while (0)

    floatx4 acc[4][4] = {};
    bf16x8 bfr[4][2];

    // Prologue: tile0 (6 loads) + tile1 B (4 loads). A(1) staged in tile0 P0.
    STAGE_BA(0, 0); STAGE_AA(0, 0); STAGE_BA(1, 64);
    asm volatile("s_waitcnt vmcnt(4)" ::: "memory");   // tile0 landed
    __builtin_amdgcn_s_barrier();

#define TILE128(bi, koN, koNN, GA1, GS) do { \
        READ_BFR2(bi); \
        bf16x8 afA[4], afB[4]; \
        READ_AF2(afA, bi, 0); \
        /* P0 */ \
        READ_AF2(afB, bi, 2); \
        if (GA1) STAGE_AA((bi) ^ 1, koN); \
        MFMA_PH2(afA, 0); \
        __builtin_amdgcn_s_barrier(); \
        /* P1 */ \
        if (GS) STAGE_BA(bi, koNN); \
        MFMA_PH2(afB, 2); \
        if (GS) asm volatile("s_waitcnt vmcnt(4)" ::: "memory"); \
        else    asm volatile("s_waitcnt vmcnt(0)" ::: "memory"); \
        __builtin_amdgcn_s_barrier(); \
    } while (0)

    for (int t = 0; t < NT; t += 2) {
        const int g1 = (t + 1) < NT, s2 = (t + 2) < NT;
        const long ko1 = (long)(t + 1) * 64;
        const long ko2 = (long)(t + 2) * 64;
        const long ko3 = (long)(t + 3) * 64;
        TILE128(0, ko1, ko2, g1, s2);
        TILE128(1, ko2, ko3, s2, s2);
    }

#pragma unroll
    for (int i = 0; i < 4; i++) {
#pragma unroll
        for (int j = 0; j < 4; j++) {
#pragma unroll
            for (int r = 0; r < 4; r++) {
                long m = tile_m + wm * 64 + i * 16 + qd * 4 + r;
                long n = tile_n + wn * 64 + j * 16 + c16;
                float v = acc[i][j][r];
                if (MODE == 1) {
                    long idx = m * (long)N + n;
                    ((float*)outp)[idx] = v + residual[idx];
                } else {
                    ((u16*)outp)[m * (long)N + n] = f2bf(v);
                }
            }
        }
    }
#undef TILE128
#undef READ_BFR2
#undef READ_AF2
#undef MFMA_PH2
#undef STAGE_AA
#undef STAGE_BA
#undef LDAF2
#undef LDBF2
#undef MFMA_
}

// ---------------- Flash-style causal attention ----------------
// grid: (16 q-tile pairs, B*H heads). Block p handles q-tiles {p, 31-p}
// (uniform 33 kv-tile iterations per block). 4 waves, 16 Q rows per wave.
// V comes PRE-TRANSPOSED: VT[vfeat][token], vfeat = h*DH+dh, token = b*L+l.
#define KSTRIDE 136   // 64x128 K tile, padded
#define VSTRIDE 72    // 128x64 V^T tile, padded
#define PSTRIDE 72    // 16x64 per-wave P tile, padded
__global__ __launch_bounds__(256) void attn_kernel(const u16* __restrict__ Q,
                                                   const u16* __restrict__ K,
                                                   const u16* __restrict__ VT,
                                                   u16* __restrict__ O) {
    __shared__ __attribute__((aligned(16))) u16 kt_lds[64 * KSTRIDE];
    __shared__ __attribute__((aligned(16))) u16 vt_lds[128 * VSTRIDE];
    __shared__ __attribute__((aligned(16))) u16 p_lds[4][16 * PSTRIDE];
    const int tid = threadIdx.x;
    const int wave = tid >> 6, lane = tid & 63;
    const int qd = lane >> 4, c16 = lane & 15;
    const int pair = blockIdx.x, bh = blockIdx.y;
    const int b = bh >> 4, h = bh & 15;
    const u16* qh = Q + (size_t)bh * L_ * DH_;
    const u16* kh = K + (size_t)bh * L_ * DH_;
    const u16* vth = VT + (size_t)h * DH_ * NTOK + (size_t)b * L_;

    for (int qsel = 0; qsel < 2; ++qsel) {
        const int qt = qsel ? (31 - pair) : pair;
        const int q0 = qt * 64;

        bf16x8 qf[4];
#pragma unroll
        for (int s = 0; s < 4; s++)
            qf[s] = *(const bf16x8*)(qh + (size_t)(q0 + wave * 16 + c16) * DH_ + s * 32 + qd * 8);

        floatx4 o_acc[8] = {};
        float m_i[4], l_i[4];
#pragma unroll
        for (int r = 0; r < 4; r++) { m_i[r] = -1e30f; l_i[r] = 0.f; }

        for (int kt = 0; kt <= qt; kt++) {
            const int kv0 = kt * 64;
#pragma unroll
            for (int s = 0; s < 4; s++) {
                int c = tid + s * 256;
                int kr = c >> 4, koff = (c & 15) * 8;
                *(int4*)&kt_lds[kr * KSTRIDE + koff] =
                    *(const int4*)(kh + (size_t)(kv0 + kr) * DH_ + koff);
                int dh = c >> 3, kv8 = (c & 7) * 8;
                *(int4*)&vt_lds[dh * VSTRIDE + kv8] =
                    *(const int4*)(vth + (size_t)dh * NTOK + kv0 + kv8);
            }
            __syncthreads();

            floatx4 s_acc[4] = {};
#pragma unroll
            for (int j = 0; j < 4; j++)
#pragma unroll
                for (int s = 0; s < 4; s++) {
                    bf16x8 kf = *(const bf16x8*)&kt_lds[(j * 16 + c16) * KSTRIDE + s * 32 + qd * 8];
                    s_acc[j] = __builtin_amdgcn_mfma_f32_16x16x32_bf16(qf[s], kf, s_acc[j], 0, 0, 0);
                }

            if (kt == qt) {
#pragma unroll
                for (int j = 0; j < 4; j++)
#pragma unroll
                    for (int r = 0; r < 4; r++) {
                        int col = j * 16 + c16;
                        int row = wave * 16 + qd * 4 + r;
                        if (col > row) s_acc[j][r] = -1e30f;
                    }
            }

            float rsum[4], alpha[4];
#pragma unroll
            for (int r = 0; r < 4; r++) {
                float mx = fmaxf(fmaxf(s_acc[0][r], s_acc[1][r]), fmaxf(s_acc[2][r], s_acc[3][r]));
#pragma unroll
                for (int d = 1; d < 16; d <<= 1) mx = fmaxf(mx, __shfl_xor(mx, d, 64));
                float mnew = fmaxf(m_i[r], mx);
                alpha[r] = __expf(m_i[r] - mnew);
                m_i[r] = mnew;
                rsum[r] = 0.f;
            }
#pragma unroll
            for (int j = 0; j < 4; j++)
#pragma unroll
                for (int r = 0; r < 4; r++) {
                    float p = __expf(s_acc[j][r] - m_i[r]);
                    s_acc[j][r] = p;
                    rsum[r] += p;
                }
#pragma unroll
            for (int r = 0; r < 4; r++) {
#pragma unroll
                for (int d = 1; d < 16; d <<= 1) rsum[r] += __shfl_xor(rsum[r], d, 64);
                l_i[r] = l_i[r] * alpha[r] + rsum[r];
            }
#pragma unroll
            for (int j8 = 0; j8 < 8; j8++)
#pragma unroll
                for (int r = 0; r < 4; r++) o_acc[j8][r] *= alpha[r];

#pragma unroll
            for (int j = 0; j < 4; j++)
#pragma unroll
                for (int r = 0; r < 4; r++)
                    p_lds[wave][(qd * 4 + r) * PSTRIDE + j * 16 + c16] = f2bf(s_acc[j][r]);

#pragma unroll
            for (int s = 0; s < 2; s++) {
                bf16x8 pf = *(const bf16x8*)&p_lds[wave][c16 * PSTRIDE + s * 32 + qd * 8];
#pragma unroll
                for (int j8 = 0; j8 < 8; j8++) {
                    bf16x8 vf = *(const bf16x8*)&vt_lds[(j8 * 16 + c16) * VSTRIDE + s * 32 + qd * 8];
                    o_acc[j8] = __builtin_amdgcn_mfma_f32_16x16x32_bf16(pf, vf, o_acc[j8], 0, 0, 0);
                }
            }
            __syncthreads();
        }

        float inv_l[4];
#pragma unroll
        for (int r = 0; r < 4; r++) inv_l[r] = 1.0f / l_i[r];
#pragma unroll
        for (int j8 = 0; j8 < 8; j8++)
#pragma unroll
            for (int r = 0; r < 4; r++) {
                int l = q0 + wave * 16 + qd * 4 + r;
                int d = h * DH_ + j8 * 16 + c16;
                O[(size_t)(b * L_ + l) * D_ + d] = f2bf(o_acc[j8][r] * inv_l[r]);
            }
    }
}

// ---------------- launch ----------------
extern "C" void kernel_launch(void* const* d_in, const int* in_sizes, int n_in,
                              void* d_out, int out_size, void* d_ws, size_t ws_size,
                              hipStream_t stream) {
    const float* x     = (const float*)d_in[0];
    const float* ln1_w = (const float*)d_in[2];
    const float* wq    = (const float*)d_in[3];
    const float* wk    = (const float*)d_in[4];
    const float* wv    = (const float*)d_in[5];
    const float* wo    = (const float*)d_in[6];
    const float* ln2_w = (const float*)d_in[7];
    const float* w_up  = (const float*)d_in[8];
    const float* w_dn  = (const float*)d_in[9];

    char* ws = (char*)d_ws;
    const size_t MB = 1024 * 1024;
    float* x2   = (float*)(ws + 0);          // 32 MB, live to end
    u16* hbuf   = (u16*)(ws + 32 * MB);      // 16 MB, h then h2
    u16* qbuf   = (u16*)(ws + 48 * MB);      // 16 MB
    u16* kbuf   = (u16*)(ws + 64 * MB);      // 16 MB
    u16* vtbuf  = (u16*)(ws + 80 * MB);      // 16 MB  V^T [D][NTOK]
    u16* attnb  = (u16*)(ws + 96 * MB);      // 16 MB
    u16* upbuf  = (u16*)(ws + 48 * MB);      // 64 MB, aliases q/k/vt/attn (dead)
    u16* wbufA  = (u16*)(ws + 112 * MB);     // 32 MB: wq+wk fused / wo / w_up / w_down
    u16* wbufC  = (u16*)(ws + 128 * MB);     // 8 MB: wv

    dim3 blk(256), blk512(512);
    const int nW = D_ * D_;      // 4M
    const int nU = DFF_ * D_;    // 16M
    // fused QK weight: [wq ; wk] = [2D, D]
    cvt_bf16<<<(nW / 4 + 255) / 256, blk, 0, stream>>>(wq, wbufA, nW / 4);
    cvt_bf16<<<(nW / 4 + 255) / 256, blk, 0, stream>>>(wk, wbufA + (size_t)nW, nW / 4);
    cvt_bf16<<<(nW / 4 + 255) / 256, blk, 0, stream>>>(wv, wbufC, nW / 4);
    rmsnorm_kernel<<<NTOK, blk, 0, stream>>>(x, ln1_w, hbuf);

    // fused Q+K projection: N = 2*D  (grid 16x16 = 256 blocks)
    gemm256<0><<<dim3(2 * D_ / 256, NTOK / 256), blk512, 0, stream>>>(
        hbuf, wbufA, qbuf, kbuf, nullptr, NTOK, 2 * D_, D_, 0.08838834764831845f);
    // V^T = Wv @ h^T : swapped operands, out [vfeat][token]; grid (16,16)=256
    gemm128n<3><<<dim3(NTOK / 256, D_ / 128), blk512, 0, stream>>>(
        wbufC, hbuf, vtbuf, nullptr, D_, NTOK, D_);

    dim3 ga(16, B_ * H_);                    // paired q-tiles x heads
    attn_kernel<<<ga, blk, 0, stream>>>(qbuf, kbuf, vtbuf, attnb);

    cvt_bf16<<<(nW / 4 + 255) / 256, blk, 0, stream>>>(wo, wbufA, nW / 4);
    // WO projection + residual: grid (8,32)=256
    gemm128n<1><<<dim3(D_ / 256, NTOK / 128), blk512, 0, stream>>>(
        attnb, wbufA, x2, x, NTOK, D_, D_);

    rmsnorm_kernel<<<NTOK, blk, 0, stream>>>(x2, ln2_w, hbuf);

    cvt_bf16<<<(nU / 4 + 255) / 256, blk, 0, stream>>>(w_up, wbufA, nU / 4);
    // up-proj + GELU: grid (32,16)=512 (2 exact rounds)
    gemm256<2><<<dim3(DFF_ / 256, NTOK / 256), blk512, 0, stream>>>(
        hbuf, wbufA, upbuf, nullptr, nullptr, NTOK, DFF_, D_, 1.0f);

    cvt_bf16<<<(nU / 4 + 255) / 256, blk, 0, stream>>>(w_dn, wbufA, nU / 4);
    // down-proj + residual: grid (8,32)=256
    gemm128n<1><<<dim3(D_ / 256, NTOK / 128), blk512, 0, stream>>>(
        upbuf, wbufA, (float*)d_out, x2, NTOK, D_, DFF_);
}